// Round 4
// baseline (1479.255 us; speedup 1.0000x reference)
//
#include <hip/hip_runtime.h>
#include <hip/hip_cooperative_groups.h>
#include <cstdint>
#include <cstddef>

namespace cg = cooperative_groups;

#define B64 64
#define TDEC 20
#define VV 12000
#define EE 256
#define HH 512
#define DD 1024
#define RR 36

typedef __attribute__((ext_vector_type(8))) short bf16x8;
typedef __attribute__((ext_vector_type(4))) float f32x4;

__device__ __forceinline__ unsigned short f2b(float f) {
    unsigned u = __float_as_uint(f);
    unsigned r = (u + 0x7FFFu + ((u >> 16) & 1u)) >> 16;
    return (unsigned short)r;
}
__device__ __forceinline__ float b2f(unsigned short h) {
    return __uint_as_float(((unsigned)h) << 16);
}

// ---------------- sort (stable argsort desc by length) ----------------
__global__ void k_sort(const int* __restrict__ cap_len,
                       const int* __restrict__ captions,
                       int* __restrict__ sind, int* __restrict__ dec_i,
                       int* __restrict__ caps_s,
                       float* __restrict__ out_dec,
                       float* __restrict__ out_sind,
                       float* __restrict__ out_caps)
{
    int i = threadIdx.x;
    __shared__ int lens[B64];
    lens[i] = cap_len[i];
    __syncthreads();
    int li = lens[i];
    int rank = 0;
    for (int j = 0; j < B64; ++j) {
        int lj = lens[j];
        if (lj > li || (lj == li && j < i)) rank++;
    }
    sind[rank] = i;
    dec_i[rank] = li - 1;
    out_dec[rank] = (float)(li - 1);
    out_sind[rank] = (float)i;
    for (int t = 0; t < 21; ++t) {
        int tok = captions[i * 21 + t];
        caps_s[rank * 21 + t] = tok;
        if (t >= 1) out_caps[rank * 20 + (t - 1)] = (float)tok;
    }
}

// ---------------- init xA (rf=0 | h0 bf16) and cT fp32 ----------------
__global__ void k_init(const float* __restrict__ h0, const int* __restrict__ sind,
                       unsigned short* __restrict__ xA, float* __restrict__ cT)
{
    int idx = blockIdx.x * blockDim.x + threadIdx.x;
    const int totX = B64 * 1536;
    if (idx < totX) {
        int b = idx / 1536, k = idx - b * 1536;
        unsigned short v = 0;
        if (k >= 1024) v = f2b(h0[sind[b] * HH + (k - 1024)]);
        xA[idx] = v;
    } else {
        int j = idx - totX;           // hp*64+b
        if (j < HH * B64) {
            int hp = j >> 6, b = j & 63;
            cT[j] = h0[sind[b] * HH + hp];
        }
    }
}

// ---------------- gather sorted object proposals -> bf16 ----------------
__global__ void k_gobjs(const float* __restrict__ objs, const int* __restrict__ sind,
                        unsigned short* __restrict__ objs_b)
{
    int idx = blockIdx.x * blockDim.x + threadIdx.x;
    if (idx >= B64 * RR * DD) return;
    int b = idx / (RR * DD);
    int rest = idx - b * (RR * DD);
    objs_b[idx] = f2b(objs[(size_t)sind[b] * (RR * DD) + rest]);
}

// ---------------- gather embeddings for all (t,b) -> bf16 ----------------
__global__ void k_gA(const float* __restrict__ embW, const int* __restrict__ caps_s,
                     unsigned short* __restrict__ AembB)
{
    int idx = blockIdx.x * blockDim.x + threadIdx.x;
    if (idx >= TDEC * B64 * EE) return;
    int tb = idx >> 8, e = idx & 255;
    int t = tb >> 6, b = tb & 63;
    int tok = caps_s[b * 21 + t];
    AembB[idx] = f2b(embW[(size_t)tok * EE + e]);
}

// ---------------- all weight conversions fused (grid-stride) ----------------
#define T_EMB  3072000
#define T_WIH  524288
#define T_RH   524288
#define T_WHT  131072
#define T_WC   3145728
#define T_ALL  (T_EMB + T_WIH + T_RH + T_WHT + T_WC)
__global__ void k_prep(const float* __restrict__ embW, const float* __restrict__ Wih,
                       const float* __restrict__ Whh, const float* __restrict__ rhW,
                       const float* __restrict__ whW,
                       unsigned short* __restrict__ embB, unsigned short* __restrict__ WihB,
                       unsigned short* __restrict__ rhW_b, unsigned short* __restrict__ whT,
                       unsigned short* __restrict__ Wc)
{
    for (int idx = blockIdx.x * blockDim.x + threadIdx.x; idx < T_ALL;
         idx += gridDim.x * blockDim.x) {
        int i = idx;
        if (i < T_EMB) { embB[i] = f2b(embW[i]); continue; }
        i -= T_EMB;
        if (i < T_WIH) {
            int row = i >> 8, col = i & 255;
            WihB[i] = f2b(Wih[(size_t)row * 1280 + col]);
            continue;
        }
        i -= T_WIH;
        if (i < T_RH) { rhW_b[i] = f2b(rhW[i]); continue; }
        i -= T_RH;
        if (i < T_WHT) {
            int e = i >> 9, k = i & 511;
            whT[i] = f2b(whW[(size_t)k * EE + e]);
            continue;
        }
        i -= T_WHT;
        int m = i / 1536, k = i - m * 1536;
        int hp = m >> 2, g = m & 3;
        int ro = g * 512 + hp;
        float v = (k < 1024) ? Wih[(size_t)ro * 1280 + 256 + k]
                             : Whh[(size_t)ro * 512 + (k - 1024)];
        Wc[i] = f2b(v);
    }
}

// ---------------- emb_sum partials + reduce (fp32 exact) ----------------
__global__ void k_embsum(const float* __restrict__ embW, float* __restrict__ partial)
{
    int e = threadIdx.x;
    int v0 = blockIdx.x * 50;
    float a = 0.0f;
    for (int v = v0; v < v0 + 50; ++v) a += embW[(size_t)v * EE + e];
    partial[blockIdx.x * EE + e] = a;
}
__global__ void k_embred(const float* __restrict__ partial, float* __restrict__ emb_sum)
{
    int e = threadIdx.x;
    float a = 0.0f;
    for (int j = 0; j < 240; ++j) a += partial[j * EE + e];
    emb_sum[e] = a;
}

// ---------------- pw[d] = emb_sum . wr_W[d,:] + V*wr_b[d] ----------------
__global__ void k_pwsum(const float* __restrict__ emb_sum, const float* __restrict__ wrW,
                        const float* __restrict__ wr_b, float* __restrict__ pw)
{
    __shared__ float es[EE];
    es[threadIdx.x] = emb_sum[threadIdx.x];
    __syncthreads();
    int d = blockIdx.x * 256 + threadIdx.x;
    float a = 0.0f;
    const float* row = wrW + (size_t)d * EE;
    for (int e = 0; e < EE; ++e) a = fmaf(es[e], row[e], a);
    pw[d] = a + 12000.0f * wr_b[d];
}

// ---------------- per-b: obj_sum -> s_wr, srb, sumv_wr, r_lin (bf16 objs) ----
__global__ void k_objpre(const unsigned short* __restrict__ objs_b, const float* __restrict__ wrW,
                         const float* __restrict__ wr_b, const float* __restrict__ pw,
                         const float* __restrict__ rW, const float* __restrict__ r_b,
                         float* __restrict__ s_wr, float* __restrict__ srb,
                         float* __restrict__ sumv, float* __restrict__ r_lin)
{
    int b = blockIdx.x, tid = threadIdx.x;
    __shared__ float os[DD];
    __shared__ float red[256];
    const unsigned short* ob = objs_b + (size_t)b * RR * DD;
    for (int d = tid; d < DD; d += 256) {
        float a = 0.0f;
        for (int r = 0; r < RR; ++r) a += b2f(ob[r * DD + d]);
        os[d] = a;
    }
    __syncthreads();
    float a = 0.0f;
    for (int d = 0; d < DD; ++d) a = fmaf(os[d], wrW[(size_t)d * EE + tid], a);
    s_wr[b * EE + tid] = a;
    float p = 0.0f;
    for (int d = tid; d < DD; d += 256) p = fmaf(os[d], wr_b[d], p);
    red[tid] = p;
    __syncthreads();
    for (int s = 128; s > 0; s >>= 1) { if (tid < s) red[tid] += red[tid + s]; __syncthreads(); }
    if (tid == 0) srb[b] = red[0];
    if (tid < RR) {
        const unsigned short* row = ob + (size_t)tid * DD;
        float sv = 0.0f, rl = 0.0f;
        for (int d = 0; d < DD; ++d) { float x = b2f(row[d]); sv = fmaf(pw[d], x, sv); rl = fmaf(rW[d], x, rl); }
        sumv[b * RR + tid] = sv;
        r_lin[b * RR + tid] = rl + r_b[0];
    }
}

// ---------------- generic bf16 MFMA GEMM: C = A*B^T + bias1 + bias2 ----------
__global__ __launch_bounds__(256) void k_bgemm(
    const unsigned short* __restrict__ A, int lda,
    const unsigned short* __restrict__ B, int ldb,
    float* __restrict__ C, int ldc, int K,
    const float* __restrict__ bias1, const float* __restrict__ bias2)
{
    int tid = threadIdx.x;
    int wv = tid >> 6, lane = tid & 63;
    int l15 = lane & 15, lg = lane >> 4;
    int m0 = blockIdx.x * 32 + (wv & 1) * 16;
    int n0 = blockIdx.y * 32 + (wv >> 1) * 16;
    const unsigned short* Ar = A + (size_t)(m0 + l15) * lda + lg * 8;
    const unsigned short* Br = B + (size_t)(n0 + l15) * ldb + lg * 8;
    f32x4 acc0 = {0.f, 0.f, 0.f, 0.f}, acc1 = {0.f, 0.f, 0.f, 0.f};
#pragma unroll 4
    for (int k0 = 0; k0 < K; k0 += 64) {
        bf16x8 a0 = *(const bf16x8*)(Ar + k0);
        bf16x8 b0 = *(const bf16x8*)(Br + k0);
        bf16x8 a1 = *(const bf16x8*)(Ar + k0 + 32);
        bf16x8 b1 = *(const bf16x8*)(Br + k0 + 32);
        acc0 = __builtin_amdgcn_mfma_f32_16x16x32_bf16(a0, b0, acc0, 0, 0, 0);
        acc1 = __builtin_amdgcn_mfma_f32_16x16x32_bf16(a1, b1, acc1, 0, 0, 0);
    }
    int n = n0 + l15;
    float badd = 0.0f;
    if (bias1) badd += bias1[n];
    if (bias2) badd += bias2[n];
#pragma unroll
    for (int r = 0; r < 4; ++r) {
        int m = m0 + 4 * lg + r;
        C[(size_t)m * ldc + n] = acc0[r] + acc1[r] + badd;
    }
}

// ---------------- fused recurrence: 20 steps, 2 phases/step, cooperative ----
__global__ __launch_bounds__(512) void k_recur(
    const unsigned short* __restrict__ Wc,
    unsigned short* __restrict__ xA, unsigned short* __restrict__ xB,
    const float* __restrict__ ge, float* __restrict__ cT,
    const int* __restrict__ dec_i,
    const unsigned short* __restrict__ objs_b,
    const float* __restrict__ rh_all,
    const float* __restrict__ sumv, const float* __restrict__ r_lin,
    const unsigned short* __restrict__ whT,
    const float* __restrict__ wh_b, const float* __restrict__ wW, const float* __restrict__ w_b,
    const float* __restrict__ emb_sum,
    const float* __restrict__ s_wr, const float* __restrict__ srb,
    unsigned short* __restrict__ Gb, float* __restrict__ g0,
    float* __restrict__ attn_out)
{
    cg::grid_group grid = cg::this_grid();
    const int tid = threadIdx.x;
    const int blk = blockIdx.x;              // 0..63
    const int wv = tid >> 6, lane = tid & 63;
    const int l15 = lane & 15, lg = lane >> 4;
    // phase-1 geometry: 512 wave-tiles (128 m-tiles x 4 n-tiles)
    const int tileid = blk * 8 + wv;
    const int m0 = (tileid >> 2) * 16;
    const int n0 = (tileid & 3) * 16;
    const int hp1 = (m0 >> 2) + lg;
    const int b1 = n0 + l15;
    const int dec1 = dec_i[b1];
    // phase-2 geometry
    const int b2 = blk;
    const int dec2 = dec_i[b2];

    __shared__ float hs[HH];
    __shared__ float rpart[RR][8];
    __shared__ float rvec_s[RR];
    __shared__ float ra_s[RR];
    __shared__ float red1[512];
    __shared__ float red2[256];
    __shared__ float up[256][2];

    for (int t = 0; t < TDEC; ++t) {
        const unsigned short* xin = (t & 1) ? xB : xA;
        unsigned short* xout = (t & 1) ? xA : xB;

        // ================= phase 1: LSTM gates + c/h update =================
        {
            const unsigned short* Ar = Wc + (size_t)(m0 + l15) * 1536 + lg * 8;
            const unsigned short* Br = xin + (size_t)(n0 + l15) * 1536 + lg * 8;
            f32x4 acc0 = {0.f, 0.f, 0.f, 0.f}, acc1 = {0.f, 0.f, 0.f, 0.f};
#pragma unroll 6
            for (int k0 = 0; k0 < 1536; k0 += 64) {
                bf16x8 a0 = *(const bf16x8*)(Ar + k0);
                bf16x8 bb0 = *(const bf16x8*)(Br + k0);
                bf16x8 a1 = *(const bf16x8*)(Ar + k0 + 32);
                bf16x8 bb1 = *(const bf16x8*)(Br + k0 + 32);
                acc0 = __builtin_amdgcn_mfma_f32_16x16x32_bf16(a0, bb0, acc0, 0, 0, 0);
                acc1 = __builtin_amdgcn_mfma_f32_16x16x32_bf16(a1, bb1, acc1, 0, 0, 0);
            }
            const float* geb = ge + ((size_t)t * B64 + b1) * 2048;
            float gi = acc0[0] + acc1[0] + geb[hp1];
            float gf = acc0[1] + acc1[1] + geb[512 + hp1];
            float gg = acc0[2] + acc1[2] + geb[1024 + hp1];
            float go = acc0[3] + acc1[3] + geb[1536 + hp1];
            float ii = 1.0f / (1.0f + expf(-gi));
            float ff = 1.0f / (1.0f + expf(-gf));
            float oo = 1.0f / (1.0f + expf(-go));
            float g2 = tanhf(gg);
            float cold = cT[hp1 * 64 + b1];
            float cn = ff * cold + ii * g2;
            float hn = oo * tanhf(cn);
            unsigned short hold = xin[(size_t)b1 * 1536 + 1024 + hp1];
            bool act = dec1 > t;
            if (act) cT[hp1 * 64 + b1] = cn;
            xout[(size_t)b1 * 1536 + 1024 + hp1] = act ? f2b(hn) : hold;
        }
        grid.sync();

        // ================= phase 2: attention / u_t / rf (block = b2) =======
        {
            float hv = b2f(xout[(size_t)b2 * 1536 + 1024 + tid]);
            hs[tid] = hv;
            red1[tid] = hv * wh_b[tid];
            __syncthreads();
            // u halves: e = tid&255, half = tid>>8 (256 k each)
            {
                int e = tid & 255, hf = tid >> 8;
                const unsigned short* wr = whT + (size_t)e * HH + hf * 256;
                const float* hq = hs + hf * 256;
                float u = 0.0f;
#pragma unroll 4
                for (int i = 0; i < 32; ++i) {
                    bf16x8 w8 = *(const bf16x8*)(wr + i * 8);
#pragma unroll
                    for (int j = 0; j < 8; ++j)
                        u = fmaf(b2f((unsigned short)w8[j]), hq[i * 8 + j], u);
                }
                up[e][hf] = u;
            }
            // rvec partials: tid < 288 -> (r, q) with 64-k chunks
            if (tid < RR * 8) {
                int r = tid >> 3, q = tid & 7;
                const float* rh = rh_all + ((size_t)b2 * RR + r) * HH + q * 64;
                const float* hq = hs + q * 64;
                float a = 0.0f;
#pragma unroll 4
                for (int k = 0; k < 64; ++k) a = fmaf(rh[k], hq[k], a);
                rpart[r][q] = a;
            }
            __syncthreads();
            float ut = 0.0f;
            if (tid < 256) {
                ut = up[tid][0] + up[tid][1] + wW[tid];
                Gb[((size_t)t * B64 + b2) * EE + tid] = f2b(ut + s_wr[b2 * EE + tid]);
                red2[tid] = ut * emb_sum[tid];
            }
            if (tid < RR) {
                float a = rpart[tid][0] + rpart[tid][1] + rpart[tid][2] + rpart[tid][3]
                        + rpart[tid][4] + rpart[tid][5] + rpart[tid][6] + rpart[tid][7];
                rvec_s[tid] = a + r_lin[b2 * RR + tid];
            }
            __syncthreads();
            for (int s = 256; s > 0; s >>= 1) {
                if (tid < s) {
                    red1[tid] += red1[tid + s];
                    if (s <= 128) red2[tid] += red2[tid + s];
                }
                __syncthreads();
            }
            // wave-parallel softmax over 36 logits (first wave)
            if (tid < 64) {
                float hwb = red1[0] + w_b[0];
                float wtsum = red2[0] + 12000.0f * hwb;
                float rv = (tid < RR) ? rvec_s[tid] : 0.0f;
                float lgv = (tid < RR) ? (wtsum + sumv[b2 * RR + tid] + rv) : -3.0e38f;
                float mx = lgv;
#pragma unroll
                for (int o = 32; o > 0; o >>= 1) mx = fmaxf(mx, __shfl_xor(mx, o));
                float ev = (tid < RR) ? __expf(lgv - mx) : 0.0f;
                float sm = ev, rvs = rv;
#pragma unroll
                for (int o = 32; o > 0; o >>= 1) { sm += __shfl_xor(sm, o); rvs += __shfl_xor(rvs, o); }
                if (tid < RR) ra_s[tid] = ev / sm;
                if (tid == 0) g0[t * B64 + b2] = hwb + srb[b2] + rvs;
            }
            __syncthreads();
            bool act = dec2 > t;
            if (tid < RR) attn_out[((size_t)b2 * TDEC + t) * RR + tid] = act ? ra_s[tid] : 0.0f;
            // rf update (2 dims per thread)
            {
                int d0 = tid * 2;
                unsigned short* dst = xout + (size_t)b2 * 1536 + d0;
                if (act) {
                    float a0 = 0.f, a1 = 0.f;
                    const unsigned short* ob = objs_b + (size_t)b2 * (RR * DD) + d0;
#pragma unroll 4
                    for (int r = 0; r < RR; ++r) {
                        ushort2 o2 = *(const ushort2*)(ob + r * DD);
                        float w = ra_s[r];
                        a0 = fmaf(w, b2f(o2.x), a0);
                        a1 = fmaf(w, b2f(o2.y), a1);
                    }
                    ushort2 w2; w2.x = f2b(a0); w2.y = f2b(a1);
                    *(ushort2*)dst = w2;
                } else {
                    *(ushort2*)dst = *(const ushort2*)(xin + (size_t)b2 * 1536 + d0);
                }
            }
        }
        grid.sync();
    }
}

// ---------------- final predictions MFMA + LDS-staged coalesced stores ------
__global__ __launch_bounds__(256) void k_preds(
    const unsigned short* __restrict__ Gb, const unsigned short* __restrict__ embB,
    const float* __restrict__ g0, const int* __restrict__ dec_i,
    float* __restrict__ out)
{
    __shared__ float outs[64 * 132];
    __shared__ float sadd[64];
    __shared__ int sact[64];
    int tid = threadIdx.x;
    int wv = tid >> 6, lane = tid & 63;
    int l15 = lane & 15, lg = lane >> 4;
    int tq = blockIdx.x;
    int n00 = blockIdx.y * 128;
    int m0w = wv * 16;
    if (tid < 64) { sadd[tid] = g0[tq * 64 + tid]; sact[tid] = dec_i[tid] > tq; }
    bf16x8 afr[8];
    const unsigned short* Ar = Gb + (size_t)(tq * 64 + m0w + l15) * EE + lg * 8;
#pragma unroll
    for (int k = 0; k < 8; ++k) afr[k] = *(const bf16x8*)(Ar + k * 32);
    const bf16x8 zb = {0, 0, 0, 0, 0, 0, 0, 0};
#pragma unroll
    for (int nf = 0; nf < 8; ++nf) {
        int nb = n00 + nf * 16 + l15;
        bool bok = nb < VV;
        const unsigned short* Br = embB + (size_t)nb * EE + lg * 8;
        f32x4 acc = {0.f, 0.f, 0.f, 0.f};
#pragma unroll
        for (int k = 0; k < 8; ++k) {
            bf16x8 bb8 = bok ? *(const bf16x8*)(Br + k * 32) : zb;
            acc = __builtin_amdgcn_mfma_f32_16x16x32_bf16(afr[k], bb8, acc, 0, 0, 0);
        }
#pragma unroll
        for (int r = 0; r < 4; ++r)
            outs[(m0w + 4 * lg + r) * 132 + nf * 16 + l15] = acc[r];
    }
    __syncthreads();
#pragma unroll
    for (int it = 0; it < 8; ++it) {
        int row = it * 8 + (tid >> 5);
        int c = (tid & 31) * 4;
        if (n00 + c < VV) {
            float add = sadd[row];
            bool a = sact[row] != 0;
            const float* src = outs + row * 132 + c;
            float4 v;
            v.x = a ? src[0] + add : 0.0f;
            v.y = a ? src[1] + add : 0.0f;
            v.z = a ? src[2] + add : 0.0f;
            v.w = a ? src[3] + add : 0.0f;
            *(float4*)(out + ((size_t)row * TDEC + tq) * VV + n00 + c) = v;
        }
    }
}

extern "C" void kernel_launch(void* const* d_in, const int* in_sizes, int n_in,
                              void* d_out, int out_size, void* d_ws, size_t ws_size,
                              hipStream_t stream)
{
    const float* h0      = (const float*)d_in[0];
    const float* objs    = (const float*)d_in[1];
    const int*   caps    = (const int*)d_in[2];
    const int*   cap_len = (const int*)d_in[3];
    const float* embW    = (const float*)d_in[4];
    const float* whW     = (const float*)d_in[5];
    const float* wh_b    = (const float*)d_in[6];
    const float* wrW     = (const float*)d_in[7];
    const float* wr_b    = (const float*)d_in[8];
    const float* rhW     = (const float*)d_in[9];
    const float* rh_b    = (const float*)d_in[10];
    const float* wW      = (const float*)d_in[11];
    const float* w_b     = (const float*)d_in[12];
    const float* rW      = (const float*)d_in[13];
    const float* r_b     = (const float*)d_in[14];
    const float* Wih     = (const float*)d_in[15];
    const float* Whh     = (const float*)d_in[16];
    const float* bih     = (const float*)d_in[17];
    const float* bhh     = (const float*)d_in[18];

    float* out = (float*)d_out;
    float* out_pred = out;                      // 64*20*12000
    float* out_attn = out + 15360000;           // 64*20*36
    float* out_caps = out + 15406080;           // 64*20
    float* out_dec  = out + 15407360;           // 64
    float* out_sind = out + 15407424;           // 64

    float* f = (float*)d_ws;
    size_t o = 0;
    float* rh_all  = f + o; o += (size_t)B64 * RR * HH;    // 1,179,648
    float* ge      = f + o; o += (size_t)TDEC * B64 * 2048;// 2,621,440
    float* cT      = f + o; o += (size_t)HH * B64;         // 32,768
    float* g0      = f + o; o += TDEC * B64;               // 1,280
    float* embpart = f + o; o += 240 * EE;                 // 61,440
    float* emb_sum = f + o; o += EE;
    float* pw      = f + o; o += DD;
    float* sumv    = f + o; o += B64 * RR;
    float* r_lin   = f + o; o += B64 * RR;
    float* s_wr    = f + o; o += B64 * EE;
    float* srb     = f + o; o += B64;
    o = (o + 3) & ~(size_t)3;
    unsigned short* us = (unsigned short*)(f + o);
    size_t uo = 0;
    unsigned short* xA     = us + uo; uo += (size_t)B64 * 1536;
    unsigned short* xB     = us + uo; uo += (size_t)B64 * 1536;
    unsigned short* objs_b = us + uo; uo += (size_t)B64 * RR * DD;
    unsigned short* AembB  = us + uo; uo += (size_t)TDEC * B64 * EE;
    unsigned short* rhW_b  = us + uo; uo += (size_t)HH * DD;
    unsigned short* embB   = us + uo; uo += (size_t)VV * EE;
    unsigned short* WihB   = us + uo; uo += (size_t)2048 * EE;
    unsigned short* whT    = us + uo; uo += (size_t)EE * HH;
    unsigned short* Wc     = us + uo; uo += (size_t)2048 * 1536;
    unsigned short* Gb     = us + uo; uo += (size_t)TDEC * B64 * EE;
    int* ibase  = (int*)(us + uo);
    int* sind   = ibase;
    int* dec_i  = ibase + 64;
    int* caps_s = ibase + 128;

    k_sort<<<1, 64, 0, stream>>>(cap_len, caps, sind, dec_i, caps_s, out_dec, out_sind, out_caps);
    k_init<<<512, 256, 0, stream>>>(h0, sind, xA, cT);
    k_gobjs<<<9216, 256, 0, stream>>>(objs, sind, objs_b);
    k_gA<<<1280, 256, 0, stream>>>(embW, caps_s, AembB);
    k_prep<<<8192, 256, 0, stream>>>(embW, Wih, Whh, rhW, whW, embB, WihB, rhW_b, whT, Wc);
    k_embsum<<<240, 256, 0, stream>>>(embW, embpart);
    k_embred<<<1, 256, 0, stream>>>(embpart, emb_sum);
    k_pwsum<<<4, 256, 0, stream>>>(emb_sum, wrW, wr_b, pw);
    k_objpre<<<64, 256, 0, stream>>>(objs_b, wrW, wr_b, pw, rW, r_b, s_wr, srb, sumv, r_lin);
    {
        dim3 g1(72, 16);   // rh_all: M=2304, N=512, K=1024
        k_bgemm<<<g1, 256, 0, stream>>>(objs_b, DD, rhW_b, DD, rh_all, HH, DD, rh_b, nullptr);
        dim3 g2(40, 64);   // ge: M=1280, N=2048, K=256
        k_bgemm<<<g2, 256, 0, stream>>>(AembB, EE, WihB, EE, ge, 2048, EE, bih, bhh);
    }
    {
        void* args[] = {
            (void*)&Wc, (void*)&xA, (void*)&xB, (void*)&ge, (void*)&cT, (void*)&dec_i,
            (void*)&objs_b, (void*)&rh_all, (void*)&sumv, (void*)&r_lin, (void*)&whT,
            (void*)&wh_b, (void*)&wW, (void*)&w_b, (void*)&emb_sum, (void*)&s_wr,
            (void*)&srb, (void*)&Gb, (void*)&g0, (void*)&out_attn
        };
        hipLaunchCooperativeKernel((const void*)k_recur, dim3(64), dim3(512), args, 0, stream);
    }
    {
        dim3 g3(20, 94);
        k_preds<<<g3, 256, 0, stream>>>(Gb, embB, g0, dec_i, out_pred);
    }
}